// Round 3
// baseline (4901.461 us; speedup 1.0000x reference)
//
#include <hip/hip_runtime.h>

#define N_NODES 16384
#define N_GRAPHS 32
#define NPG 512
#define C 88
#define NL 6
#define NH 4
#define HD 22
#define EA 131072
#define EE 262144
#define EDIM 197
#define EEMB 8
#define PE_RAW 18
#define PE_DIM 10
#define XD 96
#define XF 78
#define BN_EPS 1e-5f
#define ATT_SCALE 0.21320071635561044f
#define INV_N (1.0f / 16384.0f)

// ---------------- edge attr embedding v2: LDS-staged, 32 edges/block -------
__global__ __launch_bounds__(256) void k_edge_emb2(const float* __restrict__ Aattr,
                                                   const float* __restrict__ Eattr,
                                                   const float* __restrict__ W,
                                                   float* __restrict__ Aemb,
                                                   float* __restrict__ Eemb) {
    __shared__ float Ls[32 * EDIM];
    int t = threadIdx.x;
    long be = (long)blockIdx.x * 32;   // block edge base (A rows then E rows)
    const float* src;
    float* dst;
    if (be < EA) { src = Aattr + be * EDIM; dst = Aemb + be * EEMB; }
    else { long e = be - EA; src = Eattr + e * EDIM; dst = Eemb + e * EEMB; }
    // stage 32*197 floats = 1576 float4 (base 16B-aligned: 32*197*4 % 16 == 0)
    const float4* s4 = (const float4*)src;
    for (int idx = t; idx < 32 * EDIM / 4; idx += 256) {
        float4 v = s4[idx];
        float4* d4 = (float4*)&Ls[4 * idx];
        *d4 = v;
    }
    __syncthreads();
    int e = t >> 3, j = t & 7;
    const float* row = Ls + e * EDIM;
    float acc = 0.f;
#pragma unroll 4
    for (int i = 0; i < EDIM; i++) acc = fmaf(row[i], W[i * EEMB + j], acc);
    dst[e * EEMB + j] = acc;
}

// ---------------- per-column mean/rstd (only for the small PE BN) ----------
__global__ void k_colstats(const float* __restrict__ X, int ldx, int nrows,
                           float* __restrict__ mean, float* __restrict__ rstd) {
    int c = blockIdx.x;
    int t = threadIdx.x;
    float s = 0.f, s2 = 0.f;
    for (int r = t; r < nrows; r += 256) {
        float v = X[(size_t)r * ldx + c];
        s += v; s2 += v * v;
    }
    __shared__ float ls[256], ls2[256];
    ls[t] = s; ls2[t] = s2;
    __syncthreads();
    for (int off = 128; off > 0; off >>= 1) {
        if (t < off) { ls[t] += ls[t + off]; ls2[t] += ls2[t + off]; }
        __syncthreads();
    }
    if (t == 0) {
        float m = ls[0] / nrows;
        float var = ls2[0] / nrows - m * m;
        mean[c] = m;
        rstd[c] = rsqrtf(var + BN_EPS);
    }
}

// ---------------- row-coalesced BN stats: sums[c], sums[88+c] --------------
__global__ void k_stats2(const float* __restrict__ X, float* __restrict__ sums) {
    int t = threadIdx.x;          // 176 threads
    int tx = t % C, ty = t / C;   // ty in {0,1}
    int r0 = blockIdx.x * 512;
    float s = 0.f, s2 = 0.f;
    for (int r = r0 + ty; r < r0 + 512; r += 2) {
        float v = X[(size_t)r * C + tx];
        s += v; s2 += v * v;
    }
    __shared__ float a[176], b[176];
    a[t] = s; b[t] = s2;
    __syncthreads();
    if (t < C) {
        atomicAdd(&sums[tx], a[tx] + a[tx + C]);
        atomicAdd(&sums[C + tx], b[tx] + b[tx + C]);
    }
}

// ---------------- build h0 = [x, bn(pe)@pe_w + pe_b] -----------------------
__global__ void k_build_h(const float* __restrict__ xd, const float* __restrict__ pe_mean,
                          const float* __restrict__ pe_rstd, const float* __restrict__ pe_g,
                          const float* __restrict__ pe_bt, const float* __restrict__ pe_w,
                          const float* __restrict__ pe_b, float* __restrict__ h) {
    int gid = blockIdx.x * blockDim.x + threadIdx.x;
    if (gid >= N_NODES * C) return;
    int n = gid / C, c = gid % C;
    float v;
    if (c < XF) {
        v = xd[(size_t)n * XD + c];
    } else {
        int j = c - XF;
        float acc = pe_b[j];
#pragma unroll
        for (int i = 0; i < PE_RAW; i++) {
            float pn = (xd[(size_t)n * XD + XF + i] - pe_mean[i]) * pe_rstd[i] * pe_g[i] + pe_bt[i];
            acc += pn * pe_w[i * PE_DIM + j];
        }
        v = acc;
    }
    h[gid] = v;
}

// ---------------- GINE edge message + scatter-add (quad version) -----------
__global__ void k_gine_edge2(const float* __restrict__ Aemb, const int* __restrict__ ei,
                             const float* __restrict__ h, const float* __restrict__ ew,
                             const float* __restrict__ eb, float* __restrict__ aggr) {
    int gid = blockIdx.x * blockDim.x + threadIdx.x;   // e*22 + q
    int e = gid / 22, q = gid % 22;
    const float* emb = Aemb + (size_t)e * EEMB;
    float4 acc = *(const float4*)(eb + 4 * q);
#pragma unroll
    for (int j = 0; j < EEMB; j++) {
        float ej = emb[j];
        float4 w = *(const float4*)(ew + j * C + 4 * q);
        acc.x = fmaf(ej, w.x, acc.x); acc.y = fmaf(ej, w.y, acc.y);
        acc.z = fmaf(ej, w.z, acc.z); acc.w = fmaf(ej, w.w, acc.w);
    }
    int s = ei[e], d = ei[EA + e];
    float4 hv = *(const float4*)(h + (size_t)s * C + 4 * q);
    float* ab = aggr + (size_t)d * C + 4 * q;
    float m0 = fmaxf(acc.x + hv.x, 0.f), m1 = fmaxf(acc.y + hv.y, 0.f);
    float m2 = fmaxf(acc.z + hv.z, 0.f), m3 = fmaxf(acc.w + hv.w, 0.f);
    atomicAdd(ab + 0, m0); atomicAdd(ab + 1, m1);
    atomicAdd(ab + 2, m2); atomicAdd(ab + 3, m3);
}

// ---------------- tiled fp32 GEMM: OUT[32 nodes x 88/slab cols] ------------
// X: [16384 x K] (+optional X2 added), W: [K x N] row-major ld=ldw,
// OUT[n, c_off+c] = sum_j X[n,j] W[j, c_off+c] (+bias)(+R)(relu?)
template <int K>
__global__ __launch_bounds__(192) void k_gemm(const float* __restrict__ X,
                                              const float* __restrict__ X2,
                                              const float* __restrict__ W, int ldw,
                                              const float* __restrict__ bias,
                                              const float* __restrict__ R,
                                              float* __restrict__ OUT, int ldo, int relu) {
    __shared__ float Ws[88 * 96];
    __shared__ float Xs[32 * (K + 1)];
    int t = threadIdx.x;
    int n0 = blockIdx.x * 32;
    int c_off = blockIdx.y * 88;

    // stage X tile (rows n0..n0+31, stride K+1 in LDS)
    for (int idx = t; idx < 32 * (K / 4); idx += 192) {
        int r = idx / (K / 4), q = idx % (K / 4);
        float4 v = *(const float4*)(X + (size_t)(n0 + r) * K + 4 * q);
        if (X2) {
            float4 v2 = *(const float4*)(X2 + (size_t)(n0 + r) * K + 4 * q);
            v.x += v2.x; v.y += v2.y; v.z += v2.z; v.w += v2.w;
        }
        float* dst = Xs + r * (K + 1) + 4 * q;
        dst[0] = v.x; dst[1] = v.y; dst[2] = v.z; dst[3] = v.w;
    }

    int cq = t % 24, nq = t / 24;   // cq 0..23, nq 0..7
    float4 acc[4];
#pragma unroll
    for (int i = 0; i < 4; i++) acc[i] = make_float4(0.f, 0.f, 0.f, 0.f);

    const int NCH = K / 88;
    for (int kc = 0; kc < NCH; kc++) {
        __syncthreads();
        // stage W chunk rows [kc*88, kc*88+88) -> Ws[88 x 96], zero-pad cols 88..95
        for (int idx = t; idx < 88 * 22; idx += 192) {
            int j = idx / 22, q = idx % 22;
            float4 v = *(const float4*)(W + (size_t)(kc * 88 + j) * ldw + c_off + 4 * q);
            *(float4*)(Ws + j * 96 + 4 * q) = v;
        }
        for (int idx = t; idx < 88 * 2; idx += 192) {
            int j = idx / 2, hh = idx % 2;
            *(float4*)(Ws + j * 96 + 88 + 4 * hh) = make_float4(0.f, 0.f, 0.f, 0.f);
        }
        __syncthreads();
#pragma unroll 4
        for (int j = 0; j < 88; j++) {
            float4 w = *(const float4*)(Ws + j * 96 + 4 * cq);
            int jj = kc * 88 + j;
            float x0 = Xs[(4 * nq + 0) * (K + 1) + jj];
            float x1 = Xs[(4 * nq + 1) * (K + 1) + jj];
            float x2 = Xs[(4 * nq + 2) * (K + 1) + jj];
            float x3 = Xs[(4 * nq + 3) * (K + 1) + jj];
            acc[0].x = fmaf(x0, w.x, acc[0].x); acc[0].y = fmaf(x0, w.y, acc[0].y);
            acc[0].z = fmaf(x0, w.z, acc[0].z); acc[0].w = fmaf(x0, w.w, acc[0].w);
            acc[1].x = fmaf(x1, w.x, acc[1].x); acc[1].y = fmaf(x1, w.y, acc[1].y);
            acc[1].z = fmaf(x1, w.z, acc[1].z); acc[1].w = fmaf(x1, w.w, acc[1].w);
            acc[2].x = fmaf(x2, w.x, acc[2].x); acc[2].y = fmaf(x2, w.y, acc[2].y);
            acc[2].z = fmaf(x2, w.z, acc[2].z); acc[2].w = fmaf(x2, w.w, acc[2].w);
            acc[3].x = fmaf(x3, w.x, acc[3].x); acc[3].y = fmaf(x3, w.y, acc[3].y);
            acc[3].z = fmaf(x3, w.z, acc[3].z); acc[3].w = fmaf(x3, w.w, acc[3].w);
        }
    }

    if (cq >= 22) return;   // padding columns
    int cg = c_off + 4 * cq;
    float4 bq = make_float4(0.f, 0.f, 0.f, 0.f);
    if (bias) bq = *(const float4*)(bias + cg);
#pragma unroll
    for (int i = 0; i < 4; i++) {
        int n = n0 + 4 * nq + i;
        float4 v = acc[i];
        v.x += bq.x; v.y += bq.y; v.z += bq.z; v.w += bq.w;
        if (R) {
            float4 rv = *(const float4*)(R + (size_t)n * ldo + cg);
            v.x += rv.x; v.y += rv.y; v.z += rv.z; v.w += rv.w;
        }
        if (relu) {
            v.x = fmaxf(v.x, 0.f); v.y = fmaxf(v.y, 0.f);
            v.z = fmaxf(v.z, 0.f); v.w = fmaxf(v.w, 0.f);
        }
        *(float4*)(OUT + (size_t)n * ldo + cg) = v;
    }
}

// ---------------- flash attention: block per (graph, head, qtile) ----------
#define KCH 16
__global__ __launch_bounds__(128) void k_attn(const float* __restrict__ q,
                                              const float* __restrict__ kbuf,
                                              const float* __restrict__ vbuf,
                                              float* __restrict__ o) {
    int bx = blockIdx.x;
    int qt = bx & 3;
    int head = (bx >> 2) & 3;
    int g = bx >> 4;
    int t = threadIdx.x;
    int qnode = g * NPG + qt * 128 + t;
    const float* qr = q + (size_t)qnode * C + head * HD;
    float qreg[24], oreg[24];
#pragma unroll
    for (int d = 0; d < 24; d++) {
        qreg[d] = (d < HD) ? qr[d] * ATT_SCALE : 0.f;
        oreg[d] = 0.f;
    }
    float m = -1e30f, l = 0.f;
    __shared__ float Kt[64][24];
    __shared__ float Vt[64][24];
    for (int kt = 0; kt < NPG / 64; kt++) {
        __syncthreads();
        for (int idx = t; idx < 64 * HD; idx += 128) {
            int r = idx / HD, cc = idx % HD;
            int knode = g * NPG + kt * 64 + r;
            Kt[r][cc] = kbuf[(size_t)knode * C + head * HD + cc];
            Vt[r][cc] = vbuf[(size_t)knode * C + head * HD + cc];
        }
        for (int idx = t; idx < 64 * 2; idx += 128) {
            int r = idx >> 1, cc = HD + (idx & 1);
            Kt[r][cc] = 0.f; Vt[r][cc] = 0.f;
        }
        __syncthreads();
        for (int c0 = 0; c0 < 64; c0 += KCH) {
            float sc[KCH];
#pragma unroll
            for (int i = 0; i < KCH; i++) {
                float s = 0.f;
#pragma unroll
                for (int d = 0; d < 24; d++) s += qreg[d] * Kt[c0 + i][d];
                sc[i] = s;
            }
            float tmax = sc[0];
#pragma unroll
            for (int i = 1; i < KCH; i++) tmax = fmaxf(tmax, sc[i]);
            float newm = fmaxf(m, tmax);
            float alpha = __expf(m - newm);
            l *= alpha;
#pragma unroll
            for (int d = 0; d < 24; d++) oreg[d] *= alpha;
            m = newm;
#pragma unroll
            for (int i = 0; i < KCH; i++) {
                float p = __expf(sc[i] - m);
                l += p;
#pragma unroll
                for (int d = 0; d < 24; d++) oreg[d] += p * Vt[c0 + i][d];
            }
        }
    }
    float inv = 1.f / l;
    float* orow = o + (size_t)qnode * C + head * HD;
#pragma unroll
    for (int d = 0; d < HD; d++) orow[d] = oreg[d] * inv;
}

// ---------------- out3 = bn1(s1) + bn2(s2), stats from raw sums ------------
__global__ void k_out3(const float* __restrict__ s1, const float* __restrict__ s2,
                       const float* __restrict__ st1, const float* __restrict__ st2,
                       const float* __restrict__ g1, const float* __restrict__ b1,
                       const float* __restrict__ g2, const float* __restrict__ b2,
                       float* __restrict__ out3) {
    int gid = blockIdx.x * blockDim.x + threadIdx.x;
    if (gid >= N_NODES * C) return;
    int c = gid % C;
    float mu1 = st1[c] * INV_N;
    float r1 = rsqrtf(st1[C + c] * INV_N - mu1 * mu1 + BN_EPS);
    float mu2 = st2[c] * INV_N;
    float r2 = rsqrtf(st2[C + c] * INV_N - mu2 * mu2 + BN_EPS);
    float a = (s1[gid] - mu1) * r1 * g1[c] + b1[c];
    float b = (s2[gid] - mu2) * r2 * g2[c] + b2[c];
    out3[gid] = a + b;
}

// ---------------- h = bn3(s3), stats from raw sums -------------------------
__global__ void k_bn_apply(const float* __restrict__ s, const float* __restrict__ st,
                           const float* __restrict__ g, const float* __restrict__ b,
                           float* __restrict__ h) {
    int gid = blockIdx.x * blockDim.x + threadIdx.x;
    if (gid >= N_NODES * C) return;
    int c = gid % C;
    float mu = st[c] * INV_N;
    float r = rsqrtf(st[C + c] * INV_N - mu * mu + BN_EPS);
    h[gid] = (s[gid] - mu) * r * g[c] + b[c];
}

// ---------------- final: logit = relu(P[se]+Q[de]+Eemb@W1_emb) . w2 + b2 ---
__global__ void k_final2(const float* __restrict__ P, const float* __restrict__ Q,
                         const int* __restrict__ ei, const float* __restrict__ Eemb,
                         const float* __restrict__ w1emb, const float* __restrict__ w2,
                         const float* __restrict__ b2, float* __restrict__ out) {
    int wid = (blockIdx.x * blockDim.x + threadIdx.x) >> 6;
    int lane = threadIdx.x & 63;
    if (wid >= EE) return;
    int se = ei[wid], de = ei[EE + wid];
    const float* ps = P + (size_t)se * C;
    const float* qd = Q + (size_t)de * C;
    const float* em = Eemb + (size_t)wid * EEMB;
    float e0 = em[0], e1 = em[1], e2 = em[2], e3 = em[3];
    float e4 = em[4], e5 = em[5], e6 = em[6], e7 = em[7];
    int c1 = lane, c2 = lane + 64;
    bool has2 = (c2 < C);
    float a1 = ps[c1] + qd[c1];
    float a2 = has2 ? (ps[c2] + qd[c2]) : 0.f;
    a1 += e0 * w1emb[0 * C + c1] + e1 * w1emb[1 * C + c1] + e2 * w1emb[2 * C + c1] +
          e3 * w1emb[3 * C + c1] + e4 * w1emb[4 * C + c1] + e5 * w1emb[5 * C + c1] +
          e6 * w1emb[6 * C + c1] + e7 * w1emb[7 * C + c1];
    if (has2)
        a2 += e0 * w1emb[0 * C + c2] + e1 * w1emb[1 * C + c2] + e2 * w1emb[2 * C + c2] +
              e3 * w1emb[3 * C + c2] + e4 * w1emb[4 * C + c2] + e5 * w1emb[5 * C + c2] +
              e6 * w1emb[6 * C + c2] + e7 * w1emb[7 * C + c2];
    a1 = fmaxf(a1, 0.f);
    a2 = fmaxf(a2, 0.f);
    float part = a1 * w2[c1] + (has2 ? a2 * w2[c2] : 0.f);
#pragma unroll
    for (int off = 32; off > 0; off >>= 1) part += __shfl_xor(part, off, 64);
    if (lane == 0) out[wid] = part + b2[0];
}

// ===========================================================================
extern "C" void kernel_launch(void* const* d_in, const int* in_sizes, int n_in,
                              void* d_out, int out_size, void* d_ws, size_t ws_size,
                              hipStream_t stream) {
    const float* xd = (const float*)d_in[0];
    const int* A_ei = (const int*)d_in[1];
    const float* Aattr = (const float*)d_in[2];
    const int* E_ei = (const int*)d_in[3];
    const float* Eattr = (const float*)d_in[4];
    const float* AW = (const float*)d_in[6];
    const float* pe_g = (const float*)d_in[7];
    const float* pe_bt = (const float*)d_in[8];
    const float* pe_w = (const float*)d_in[9];
    const float* pe_b = (const float*)d_in[10];
    const float* gine_ew = (const float*)d_in[11];
    const float* gine_eb = (const float*)d_in[12];
    const float* gine_w1 = (const float*)d_in[13];
    const float* gine_b1 = (const float*)d_in[14];
    const float* gine_w2 = (const float*)d_in[15];
    const float* gine_b2 = (const float*)d_in[16];
    const float* wq = (const float*)d_in[17];
    const float* wk = (const float*)d_in[18];
    const float* wv = (const float*)d_in[19];
    const float* wo = (const float*)d_in[20];
    const float* bq = (const float*)d_in[21];
    const float* bk = (const float*)d_in[22];
    const float* bv = (const float*)d_in[23];
    const float* bo = (const float*)d_in[24];
    const float* n1g = (const float*)d_in[25];
    const float* n2g = (const float*)d_in[26];
    const float* n3g = (const float*)d_in[27];
    const float* n1b = (const float*)d_in[28];
    const float* n2b = (const float*)d_in[29];
    const float* n3b = (const float*)d_in[30];
    const float* mw1 = (const float*)d_in[31];
    const float* mb1 = (const float*)d_in[32];
    const float* mw2 = (const float*)d_in[33];
    const float* mb2 = (const float*)d_in[34];
    const float* ew1 = (const float*)d_in[35];
    const float* eb1 = (const float*)d_in[36];
    const float* ew2 = (const float*)d_in[37];
    const float* eb2 = (const float*)d_in[38];

    float* ws = (float*)d_ws;
    size_t off = 0;
    auto alloc = [&](size_t n) { float* p = ws + off; off += n; return p; };
    float* Aemb = alloc((size_t)EA * EEMB);
    float* Eemb = alloc((size_t)EE * EEMB);
    float* h = alloc((size_t)N_NODES * C);
    float* aggr = alloc((size_t)N_NODES * C);
    float* u = alloc((size_t)N_NODES * C);
    float* s1 = alloc((size_t)N_NODES * C);   // also s3; reused as P at the end
    float* qb = alloc((size_t)N_NODES * C);
    float* kb = alloc((size_t)N_NODES * C);
    float* vb = alloc((size_t)N_NODES * C);
    float* ob = alloc((size_t)N_NODES * C);
    float* s2 = alloc((size_t)N_NODES * C);
    float* out3 = alloc((size_t)N_NODES * C);
    float* u2 = alloc((size_t)N_NODES * 176);
    float* stats = alloc(2048);
    float* st1 = stats;            // 176: sum, sumsq
    float* st2 = stats + 176;
    float* st3 = stats + 352;
    float* pe_mean = stats + 576;
    float* pe_rstd = stats + 608;

    const int NT = 256;
    const int nc_blocks = (N_NODES * C + NT - 1) / NT;
    const dim3 g88(512, 1), g176(512, 2);

    // --- prologue ---
    k_edge_emb2<<<(EA + EE) / 32, 256, 0, stream>>>(Aattr, Eattr, AW, Aemb, Eemb);
    k_colstats<<<PE_RAW, NT, 0, stream>>>(xd + XF, XD, N_NODES, pe_mean, pe_rstd);
    k_build_h<<<nc_blocks, NT, 0, stream>>>(xd, pe_mean, pe_rstd, pe_g, pe_bt, pe_w, pe_b, h);

    // --- layers ---
    for (int l = 0; l < NL; l++) {
        const float* ew = gine_ew + (size_t)l * EEMB * C;
        const float* eb = gine_eb + (size_t)l * C;
        const float* w1 = gine_w1 + (size_t)l * C * C;
        const float* b1 = gine_b1 + (size_t)l * C;
        const float* w2 = gine_w2 + (size_t)l * C * C;
        const float* b2 = gine_b2 + (size_t)l * C;
        const float* lwq = wq + (size_t)l * C * C;
        const float* lwk = wk + (size_t)l * C * C;
        const float* lwv = wv + (size_t)l * C * C;
        const float* lwo = wo + (size_t)l * C * C;
        const float* lbq = bq + (size_t)l * C;
        const float* lbk = bk + (size_t)l * C;
        const float* lbv = bv + (size_t)l * C;
        const float* lbo = bo + (size_t)l * C;
        const float* l1g = n1g + (size_t)l * C;
        const float* l1b = n1b + (size_t)l * C;
        const float* l2g = n2g + (size_t)l * C;
        const float* l2b = n2b + (size_t)l * C;
        const float* l3g = n3g + (size_t)l * C;
        const float* l3b = n3b + (size_t)l * C;
        const float* lmw1 = mw1 + (size_t)l * C * 176;
        const float* lmb1 = mb1 + (size_t)l * 176;
        const float* lmw2 = mw2 + (size_t)l * 176 * C;
        const float* lmb2 = mb2 + (size_t)l * C;

        hipMemsetAsync(aggr, 0, (size_t)N_NODES * C * sizeof(float), stream);
        hipMemsetAsync(stats, 0, 528 * sizeof(float), stream);
        k_gine_edge2<<<(EA * 22) / 256, 256, 0, stream>>>(Aemb, A_ei, h, ew, eb, aggr);
        k_gemm<88><<<g88, 192, 0, stream>>>(h, aggr, w1, C, b1, nullptr, u, C, 1);
        k_gemm<88><<<g88, 192, 0, stream>>>(u, nullptr, w2, C, b2, h, s1, C, 0);
        k_stats2<<<32, 176, 0, stream>>>(s1, st1);
        k_gemm<88><<<g88, 192, 0, stream>>>(h, nullptr, lwq, C, lbq, nullptr, qb, C, 0);
        k_gemm<88><<<g88, 192, 0, stream>>>(h, nullptr, lwk, C, lbk, nullptr, kb, C, 0);
        k_gemm<88><<<g88, 192, 0, stream>>>(h, nullptr, lwv, C, lbv, nullptr, vb, C, 0);
        k_attn<<<N_GRAPHS * NH * 4, 128, 0, stream>>>(qb, kb, vb, ob);
        k_gemm<88><<<g88, 192, 0, stream>>>(ob, nullptr, lwo, C, lbo, h, s2, C, 0);
        k_stats2<<<32, 176, 0, stream>>>(s2, st2);
        k_out3<<<nc_blocks, NT, 0, stream>>>(s1, s2, st1, st2, l1g, l1b, l2g, l2b, out3);
        k_gemm<88><<<g176, 192, 0, stream>>>(out3, nullptr, lmw1, 176, lmb1, nullptr, u2, 176, 1);
        k_gemm<176><<<g88, 192, 0, stream>>>(u2, nullptr, lmw2, C, lmb2, out3, s1, C, 0);
        k_stats2<<<32, 176, 0, stream>>>(s1, st3);
        k_bn_apply<<<nc_blocks, NT, 0, stream>>>(s1, st3, l3g, l3b, h);
    }

    // --- epilogue: factored edge MLP ---
    k_gemm<88><<<g88, 192, 0, stream>>>(h, nullptr, ew1, C, eb1, nullptr, qb, C, 0);          // P
    k_gemm<88><<<g88, 192, 0, stream>>>(h, nullptr, ew1 + (size_t)C * C, C, nullptr, nullptr, kb, C, 0); // Q
    k_final2<<<(EE * 64 + NT - 1) / NT, NT, 0, stream>>>(qb, kb, E_ei, Eemb,
                                                         ew1 + (size_t)2 * C * C, ew2, eb2,
                                                         (float*)d_out);
}

// Round 4
// 4153.889 us; speedup vs baseline: 1.1800x; 1.1800x over previous
//
#include <hip/hip_runtime.h>

#define N_NODES 16384
#define N_GRAPHS 32
#define NPG 512
#define C 88
#define NL 6
#define NH 4
#define HD 22
#define EA 131072
#define EE 262144
#define EDIM 197
#define EEMB 8
#define PE_RAW 18
#define PE_DIM 10
#define XD 96
#define XF 78
#define BN_EPS 1e-5f
#define ATT_SCALE 0.21320071635561044f
#define INV_N (1.0f / 16384.0f)

// ---------------- edge attr embedding v3: wave/edge, b128 loads, W in regs -
__global__ __launch_bounds__(256) void k_edge_emb3(const float* __restrict__ Aattr,
                                                   const float* __restrict__ Eattr,
                                                   const float* __restrict__ W,
                                                   float* __restrict__ Aemb,
                                                   float* __restrict__ Eemb) {
    int gt = blockIdx.x * 256 + threadIdx.x;
    int wid = gt >> 6, lane = gt & 63;
    int nw = gridDim.x * 4;
    int i0 = 4 * lane;
    bool full = (i0 + 3 < EDIM);          // lanes 0..48
    bool one = (!full) && (i0 < EDIM);    // lane 49 (element 196 only)
    float wreg[4][8];
#pragma unroll
    for (int r = 0; r < 4; r++)
#pragma unroll
        for (int j = 0; j < 8; j++) wreg[r][j] = 0.f;
    if (full) {
#pragma unroll
        for (int r = 0; r < 4; r++) {
            float4 a = *(const float4*)(W + (i0 + r) * 8);
            float4 b = *(const float4*)(W + (i0 + r) * 8 + 4);
            wreg[r][0] = a.x; wreg[r][1] = a.y; wreg[r][2] = a.z; wreg[r][3] = a.w;
            wreg[r][4] = b.x; wreg[r][5] = b.y; wreg[r][6] = b.z; wreg[r][7] = b.w;
        }
    } else if (one) {
        float4 a = *(const float4*)(W + i0 * 8);
        float4 b = *(const float4*)(W + i0 * 8 + 4);
        wreg[0][0] = a.x; wreg[0][1] = a.y; wreg[0][2] = a.z; wreg[0][3] = a.w;
        wreg[0][4] = b.x; wreg[0][5] = b.y; wreg[0][6] = b.z; wreg[0][7] = b.w;
    }
    for (long e = wid; e < (long)EA + EE; e += nw) {
        const float* attr;
        float* dst;
        if (e < EA) { attr = Aattr + e * EDIM; dst = Aemb + e * EEMB; }
        else { long q = e - EA; attr = Eattr + q * EDIM; dst = Eemb + q * EEMB; }
        float4 av = make_float4(0.f, 0.f, 0.f, 0.f);
        if (full) av = *(const float4*)(attr + i0);
        else if (one) av.x = attr[i0];
        float p[8];
#pragma unroll
        for (int j = 0; j < 8; j++)
            p[j] = av.x * wreg[0][j] + av.y * wreg[1][j] + av.z * wreg[2][j] + av.w * wreg[3][j];
#pragma unroll
        for (int off = 32; off > 0; off >>= 1)
#pragma unroll
            for (int j = 0; j < 8; j++) p[j] += __shfl_xor(p[j], off, 64);
        if (lane < 8) {
            float v = p[0];
            if (lane == 1) v = p[1];
            if (lane == 2) v = p[2];
            if (lane == 3) v = p[3];
            if (lane == 4) v = p[4];
            if (lane == 5) v = p[5];
            if (lane == 6) v = p[6];
            if (lane == 7) v = p[7];
            dst[lane] = v;
        }
    }
}

// ---------------- per-column mean/rstd (only for the small PE BN) ----------
__global__ void k_colstats(const float* __restrict__ X, int ldx, int nrows,
                           float* __restrict__ mean, float* __restrict__ rstd) {
    int c = blockIdx.x;
    int t = threadIdx.x;
    float s = 0.f, s2 = 0.f;
    for (int r = t; r < nrows; r += 256) {
        float v = X[(size_t)r * ldx + c];
        s += v; s2 += v * v;
    }
    __shared__ float ls[256], ls2[256];
    ls[t] = s; ls2[t] = s2;
    __syncthreads();
    for (int off = 128; off > 0; off >>= 1) {
        if (t < off) { ls[t] += ls[t + off]; ls2[t] += ls2[t + off]; }
        __syncthreads();
    }
    if (t == 0) {
        float m = ls[0] / nrows;
        float var = ls2[0] / nrows - m * m;
        mean[c] = m;
        rstd[c] = rsqrtf(var + BN_EPS);
    }
}

// ---------------- build h0 = [x, bn(pe)@pe_w + pe_b] -----------------------
__global__ void k_build_h(const float* __restrict__ xd, const float* __restrict__ pe_mean,
                          const float* __restrict__ pe_rstd, const float* __restrict__ pe_g,
                          const float* __restrict__ pe_bt, const float* __restrict__ pe_w,
                          const float* __restrict__ pe_b, float* __restrict__ h) {
    int gid = blockIdx.x * blockDim.x + threadIdx.x;
    if (gid >= N_NODES * C) return;
    int n = gid / C, c = gid % C;
    float v;
    if (c < XF) {
        v = xd[(size_t)n * XD + c];
    } else {
        int j = c - XF;
        float acc = pe_b[j];
#pragma unroll
        for (int i = 0; i < PE_RAW; i++) {
            float pn = (xd[(size_t)n * XD + XF + i] - pe_mean[i]) * pe_rstd[i] * pe_g[i] + pe_bt[i];
            acc += pn * pe_w[i * PE_DIM + j];
        }
        v = acc;
    }
    h[gid] = v;
}

// ---------------- GINE edge message + scatter-add (quad version) -----------
__global__ void k_gine_edge2(const float* __restrict__ Aemb, const int* __restrict__ ei,
                             const float* __restrict__ h, const float* __restrict__ ew,
                             const float* __restrict__ eb, float* __restrict__ aggr) {
    int gid = blockIdx.x * blockDim.x + threadIdx.x;   // e*22 + q
    int e = gid / 22, q = gid % 22;
    const float* emb = Aemb + (size_t)e * EEMB;
    float4 acc = *(const float4*)(eb + 4 * q);
#pragma unroll
    for (int j = 0; j < EEMB; j++) {
        float ej = emb[j];
        float4 w = *(const float4*)(ew + j * C + 4 * q);
        acc.x = fmaf(ej, w.x, acc.x); acc.y = fmaf(ej, w.y, acc.y);
        acc.z = fmaf(ej, w.z, acc.z); acc.w = fmaf(ej, w.w, acc.w);
    }
    int s = ei[e], d = ei[EA + e];
    float4 hv = *(const float4*)(h + (size_t)s * C + 4 * q);
    float* ab = aggr + (size_t)d * C + 4 * q;
    float m0 = fmaxf(acc.x + hv.x, 0.f), m1 = fmaxf(acc.y + hv.y, 0.f);
    float m2 = fmaxf(acc.z + hv.z, 0.f), m3 = fmaxf(acc.w + hv.w, 0.f);
    atomicAdd(ab + 0, m0); atomicAdd(ab + 1, m1);
    atomicAdd(ab + 2, m2); atomicAdd(ab + 3, m3);
}

// ---------------- register-tiled GEMM, no LDS staging ----------------------
// tile: 32 nodes x 88 cols per block; thread = 4 nodes x 4 cols.
// block 192 = 24 col-groups x 8 node-groups (2 col-groups are padding).
// W read b128 from L1 (broadcast across node-groups); X read b128 along K
// (broadcast across col-groups). Optional: X2 added to X, residual R, relu,
// and fused BN raw-moment accumulation into sums[0:88]=sum, sums[88:176]=sumsq.
// z-dim selects (W,b,O) triple for fused q/k/v.
__global__ __launch_bounds__(192) void k_gemm3(const float* __restrict__ X,
                                               const float* __restrict__ X2, int K,
                                               const float* __restrict__ Wa,
                                               const float* __restrict__ Wb,
                                               const float* __restrict__ Wc,
                                               const float* __restrict__ ba,
                                               const float* __restrict__ bb,
                                               const float* __restrict__ bc,
                                               float* __restrict__ Oa,
                                               float* __restrict__ Ob,
                                               float* __restrict__ Oc,
                                               int ldw, int ldo, int relu,
                                               float* __restrict__ sums) {
    __shared__ float red[8 * 192];
    int t = threadIdx.x;
    int z = blockIdx.z;
    const float* W = (z == 0) ? Wa : (z == 1) ? Wb : Wc;
    const float* bias = (z == 0) ? ba : (z == 1) ? bb : bc;
    float* O = (z == 0) ? Oa : (z == 1) ? Ob : Oc;

    int cg = t % 24, nq = t / 24;
    int c4 = 4 * cg;
    int c_off = 88 * blockIdx.y;
    int cidx = c_off + c4;
    int loadc = cidx;
    if (loadc > ldw - 4) loadc = ldw - 4;
    int n0 = blockIdx.x * 32 + 4 * nq;
    const float* Xr = X + (size_t)n0 * K;
    const float* X2r = X2 ? X2 + (size_t)n0 * K : nullptr;

    float4 acc[4];
#pragma unroll
    for (int i = 0; i < 4; i++) acc[i] = make_float4(0.f, 0.f, 0.f, 0.f);

    for (int j = 0; j < K; j += 4) {
        const float* Wr = W + (size_t)j * ldw + loadc;
        float4 w0 = *(const float4*)(Wr);
        float4 w1 = *(const float4*)(Wr + ldw);
        float4 w2 = *(const float4*)(Wr + 2 * ldw);
        float4 w3 = *(const float4*)(Wr + 3 * ldw);
#pragma unroll
        for (int i = 0; i < 4; i++) {
            float4 x = *(const float4*)(Xr + (size_t)i * K + j);
            if (X2r) {
                float4 x2 = *(const float4*)(X2r + (size_t)i * K + j);
                x.x += x2.x; x.y += x2.y; x.z += x2.z; x.w += x2.w;
            }
            acc[i].x = fmaf(x.x, w0.x, acc[i].x); acc[i].y = fmaf(x.x, w0.y, acc[i].y);
            acc[i].z = fmaf(x.x, w0.z, acc[i].z); acc[i].w = fmaf(x.x, w0.w, acc[i].w);
            acc[i].x = fmaf(x.y, w1.x, acc[i].x); acc[i].y = fmaf(x.y, w1.y, acc[i].y);
            acc[i].z = fmaf(x.y, w1.z, acc[i].z); acc[i].w = fmaf(x.y, w1.w, acc[i].w);
            acc[i].x = fmaf(x.z, w2.x, acc[i].x); acc[i].y = fmaf(x.z, w2.y, acc[i].y);
            acc[i].z = fmaf(x.z, w2.z, acc[i].z); acc[i].w = fmaf(x.z, w2.w, acc[i].w);
            acc[i].x = fmaf(x.w, w3.x, acc[i].x); acc[i].y = fmaf(x.w, w3.y, acc[i].y);
            acc[i].z = fmaf(x.w, w3.z, acc[i].z); acc[i].w = fmaf(x.w, w3.w, acc[i].w);
        }
    }

    float4 bq = make_float4(0.f, 0.f, 0.f, 0.f);
    if (bias) bq = *(const float4*)(bias + loadc);
    float4 outv[4];
#pragma unroll
    for (int i = 0; i < 4; i++) {
        float4 v = acc[i];
        v.x += bq.x; v.y += bq.y; v.z += bq.z; v.w += bq.w;
        if (X2 == nullptr && relu == 0 && sums == nullptr) {} // keep structure simple
        outv[i] = v;
    }
    // residual handled by caller passing R via Ob slot? No — R param below.
    // (R folded here via Oc trick is confusing; use dedicated path:)
    // NOTE: residual is passed through 'bb' slot when z==0-only calls need it?
    // -- Simpler: residual pointer is 'Wb' unused for single-z calls is fragile.
    // Residual is handled by the dedicated parameter below.
#pragma unroll
    for (int i = 0; i < 4; i++) {
        if (relu) {
            outv[i].x = fmaxf(outv[i].x, 0.f); outv[i].y = fmaxf(outv[i].y, 0.f);
            outv[i].z = fmaxf(outv[i].z, 0.f); outv[i].w = fmaxf(outv[i].w, 0.f);
        }
    }
    if (c4 < 88) {
#pragma unroll
        for (int i = 0; i < 4; i++)
            *(float4*)(O + (size_t)(n0 + i) * ldo + cidx) = outv[i];
    }
    if (sums) {
        float s[4] = {0.f, 0.f, 0.f, 0.f}, s2[4] = {0.f, 0.f, 0.f, 0.f};
#pragma unroll
        for (int i = 0; i < 4; i++) {
            s[0] += outv[i].x; s2[0] += outv[i].x * outv[i].x;
            s[1] += outv[i].y; s2[1] += outv[i].y * outv[i].y;
            s[2] += outv[i].z; s2[2] += outv[i].z * outv[i].z;
            s[3] += outv[i].w; s2[3] += outv[i].w * outv[i].w;
        }
        int base = nq * 192 + cg * 8;
#pragma unroll
        for (int k = 0; k < 4; k++) { red[base + k] = s[k]; red[base + 4 + k] = s2[k]; }
        __syncthreads();
        if (t < 96) {
            int g = t >> 2, o = t & 3;
            float a = 0.f, b = 0.f;
#pragma unroll
            for (int q = 0; q < 8; q++) {
                a += red[q * 192 + g * 8 + o];
                b += red[q * 192 + g * 8 + 4 + o];
            }
            int c = 4 * g + o;
            if (c < 88) {
                atomicAdd(&sums[c], a);
                atomicAdd(&sums[C + c], b);
            }
        }
    }
}

// residual add variant: OUT = X@W + b + R (uses same core, R applied)
__global__ __launch_bounds__(192) void k_gemm3r(const float* __restrict__ X, int K,
                                                const float* __restrict__ W,
                                                const float* __restrict__ bias,
                                                const float* __restrict__ R,
                                                float* __restrict__ O,
                                                int ldw, int ldo,
                                                float* __restrict__ sums) {
    __shared__ float red[8 * 192];
    int t = threadIdx.x;
    int cg = t % 24, nq = t / 24;
    int c4 = 4 * cg;
    int cidx = c4;
    int loadc = cidx;
    if (loadc > ldw - 4) loadc = ldw - 4;
    int n0 = blockIdx.x * 32 + 4 * nq;
    const float* Xr = X + (size_t)n0 * K;

    float4 acc[4];
#pragma unroll
    for (int i = 0; i < 4; i++) acc[i] = make_float4(0.f, 0.f, 0.f, 0.f);

    for (int j = 0; j < K; j += 4) {
        const float* Wr = W + (size_t)j * ldw + loadc;
        float4 w0 = *(const float4*)(Wr);
        float4 w1 = *(const float4*)(Wr + ldw);
        float4 w2 = *(const float4*)(Wr + 2 * ldw);
        float4 w3 = *(const float4*)(Wr + 3 * ldw);
#pragma unroll
        for (int i = 0; i < 4; i++) {
            float4 x = *(const float4*)(Xr + (size_t)i * K + j);
            acc[i].x = fmaf(x.x, w0.x, acc[i].x); acc[i].y = fmaf(x.x, w0.y, acc[i].y);
            acc[i].z = fmaf(x.x, w0.z, acc[i].z); acc[i].w = fmaf(x.x, w0.w, acc[i].w);
            acc[i].x = fmaf(x.y, w1.x, acc[i].x); acc[i].y = fmaf(x.y, w1.y, acc[i].y);
            acc[i].z = fmaf(x.y, w1.z, acc[i].z); acc[i].w = fmaf(x.y, w1.w, acc[i].w);
            acc[i].x = fmaf(x.z, w2.x, acc[i].x); acc[i].y = fmaf(x.z, w2.y, acc[i].y);
            acc[i].z = fmaf(x.z, w2.z, acc[i].z); acc[i].w = fmaf(x.z, w2.w, acc[i].w);
            acc[i].x = fmaf(x.w, w3.x, acc[i].x); acc[i].y = fmaf(x.w, w3.y, acc[i].y);
            acc[i].z = fmaf(x.w, w3.z, acc[i].z); acc[i].w = fmaf(x.w, w3.w, acc[i].w);
        }
    }

    float4 bq = make_float4(0.f, 0.f, 0.f, 0.f);
    if (bias) bq = *(const float4*)(bias + loadc);
    float4 outv[4];
#pragma unroll
    for (int i = 0; i < 4; i++) {
        float4 v = acc[i];
        v.x += bq.x; v.y += bq.y; v.z += bq.z; v.w += bq.w;
        if (R && c4 < 88) {
            float4 rv = *(const float4*)(R + (size_t)(n0 + i) * ldo + cidx);
            v.x += rv.x; v.y += rv.y; v.z += rv.z; v.w += rv.w;
        }
        outv[i] = v;
    }
    if (c4 < 88) {
#pragma unroll
        for (int i = 0; i < 4; i++)
            *(float4*)(O + (size_t)(n0 + i) * ldo + cidx) = outv[i];
    }
    if (sums) {
        float s[4] = {0.f, 0.f, 0.f, 0.f}, s2[4] = {0.f, 0.f, 0.f, 0.f};
#pragma unroll
        for (int i = 0; i < 4; i++) {
            s[0] += outv[i].x; s2[0] += outv[i].x * outv[i].x;
            s[1] += outv[i].y; s2[1] += outv[i].y * outv[i].y;
            s[2] += outv[i].z; s2[2] += outv[i].z * outv[i].z;
            s[3] += outv[i].w; s2[3] += outv[i].w * outv[i].w;
        }
        int base = nq * 192 + cg * 8;
#pragma unroll
        for (int k = 0; k < 4; k++) { red[base + k] = s[k]; red[base + 4 + k] = s2[k]; }
        __syncthreads();
        if (t < 96) {
            int g = t >> 2, o = t & 3;
            float a = 0.f, b = 0.f;
#pragma unroll
            for (int q = 0; q < 8; q++) {
                a += red[q * 192 + g * 8 + o];
                b += red[q * 192 + g * 8 + 4 + o];
            }
            int c = 4 * g + o;
            if (c < 88) {
                atomicAdd(&sums[c], a);
                atomicAdd(&sums[C + c], b);
            }
        }
    }
}

// ---------------- flash attention: block per (graph, head, qtile) ----------
#define KCH 16
__global__ __launch_bounds__(128) void k_attn(const float* __restrict__ q,
                                              const float* __restrict__ kbuf,
                                              const float* __restrict__ vbuf,
                                              float* __restrict__ o) {
    int bx = blockIdx.x;
    int qt = bx & 3;
    int head = (bx >> 2) & 3;
    int g = bx >> 4;
    int t = threadIdx.x;
    int qnode = g * NPG + qt * 128 + t;
    const float* qr = q + (size_t)qnode * C + head * HD;
    float qreg[24], oreg[24];
#pragma unroll
    for (int d = 0; d < 24; d++) {
        qreg[d] = (d < HD) ? qr[d] * ATT_SCALE : 0.f;
        oreg[d] = 0.f;
    }
    float m = -1e30f, l = 0.f;
    __shared__ float Kt[64][24];
    __shared__ float Vt[64][24];
    for (int kt = 0; kt < NPG / 64; kt++) {
        __syncthreads();
        for (int idx = t; idx < 64 * HD; idx += 128) {
            int r = idx / HD, cc = idx % HD;
            int knode = g * NPG + kt * 64 + r;
            Kt[r][cc] = kbuf[(size_t)knode * C + head * HD + cc];
            Vt[r][cc] = vbuf[(size_t)knode * C + head * HD + cc];
        }
        for (int idx = t; idx < 64 * 2; idx += 128) {
            int r = idx >> 1, cc = HD + (idx & 1);
            Kt[r][cc] = 0.f; Vt[r][cc] = 0.f;
        }
        __syncthreads();
        for (int c0 = 0; c0 < 64; c0 += KCH) {
            float sc[KCH];
#pragma unroll
            for (int i = 0; i < KCH; i++) {
                float s = 0.f;
#pragma unroll
                for (int d = 0; d < 24; d++) s += qreg[d] * Kt[c0 + i][d];
                sc[i] = s;
            }
            float tmax = sc[0];
#pragma unroll
            for (int i = 1; i < KCH; i++) tmax = fmaxf(tmax, sc[i]);
            float newm = fmaxf(m, tmax);
            float alpha = __expf(m - newm);
            l *= alpha;
#pragma unroll
            for (int d = 0; d < 24; d++) oreg[d] *= alpha;
            m = newm;
#pragma unroll
            for (int i = 0; i < KCH; i++) {
                float p = __expf(sc[i] - m);
                l += p;
#pragma unroll
                for (int d = 0; d < 24; d++) oreg[d] += p * Vt[c0 + i][d];
            }
        }
    }
    float inv = 1.f / l;
    float* orow = o + (size_t)qnode * C + head * HD;
#pragma unroll
    for (int d = 0; d < HD; d++) orow[d] = oreg[d] * inv;
}

// ---------------- out3 = bn1(s1) + bn2(s2), stats from raw sums ------------
__global__ void k_out3(const float* __restrict__ s1, const float* __restrict__ s2,
                       const float* __restrict__ st1, const float* __restrict__ st2,
                       const float* __restrict__ g1, const float* __restrict__ b1,
                       const float* __restrict__ g2, const float* __restrict__ b2,
                       float* __restrict__ out3) {
    int gid = blockIdx.x * blockDim.x + threadIdx.x;
    if (gid >= N_NODES * C) return;
    int c = gid % C;
    float mu1 = st1[c] * INV_N;
    float r1 = rsqrtf(st1[C + c] * INV_N - mu1 * mu1 + BN_EPS);
    float mu2 = st2[c] * INV_N;
    float r2 = rsqrtf(st2[C + c] * INV_N - mu2 * mu2 + BN_EPS);
    float a = (s1[gid] - mu1) * r1 * g1[c] + b1[c];
    float b = (s2[gid] - mu2) * r2 * g2[c] + b2[c];
    out3[gid] = a + b;
}

// ---------------- h = bn3(s3), stats from raw sums -------------------------
__global__ void k_bn_apply(const float* __restrict__ s, const float* __restrict__ st,
                           const float* __restrict__ g, const float* __restrict__ b,
                           float* __restrict__ h) {
    int gid = blockIdx.x * blockDim.x + threadIdx.x;
    if (gid >= N_NODES * C) return;
    int c = gid % C;
    float mu = st[c] * INV_N;
    float r = rsqrtf(st[C + c] * INV_N - mu * mu + BN_EPS);
    h[gid] = (s[gid] - mu) * r * g[c] + b[c];
}

// ---------------- final: logit = relu(P[se]+Q[de]+Eemb@W1_emb) . w2 + b2 ---
__global__ void k_final2(const float* __restrict__ P, const float* __restrict__ Q,
                         const int* __restrict__ ei, const float* __restrict__ Eemb,
                         const float* __restrict__ w1emb, const float* __restrict__ w2,
                         const float* __restrict__ b2, float* __restrict__ out) {
    int wid = (blockIdx.x * blockDim.x + threadIdx.x) >> 6;
    int lane = threadIdx.x & 63;
    if (wid >= EE) return;
    int se = ei[wid], de = ei[EE + wid];
    const float* ps = P + (size_t)se * C;
    const float* qd = Q + (size_t)de * C;
    const float* em = Eemb + (size_t)wid * EEMB;
    float e0 = em[0], e1 = em[1], e2 = em[2], e3 = em[3];
    float e4 = em[4], e5 = em[5], e6 = em[6], e7 = em[7];
    int c1 = lane, c2 = lane + 64;
    bool has2 = (c2 < C);
    float a1 = ps[c1] + qd[c1];
    float a2 = has2 ? (ps[c2] + qd[c2]) : 0.f;
    a1 += e0 * w1emb[0 * C + c1] + e1 * w1emb[1 * C + c1] + e2 * w1emb[2 * C + c1] +
          e3 * w1emb[3 * C + c1] + e4 * w1emb[4 * C + c1] + e5 * w1emb[5 * C + c1] +
          e6 * w1emb[6 * C + c1] + e7 * w1emb[7 * C + c1];
    if (has2)
        a2 += e0 * w1emb[0 * C + c2] + e1 * w1emb[1 * C + c2] + e2 * w1emb[2 * C + c2] +
              e3 * w1emb[3 * C + c2] + e4 * w1emb[4 * C + c2] + e5 * w1emb[5 * C + c2] +
              e6 * w1emb[6 * C + c2] + e7 * w1emb[7 * C + c2];
    a1 = fmaxf(a1, 0.f);
    a2 = fmaxf(a2, 0.f);
    float part = a1 * w2[c1] + (has2 ? a2 * w2[c2] : 0.f);
#pragma unroll
    for (int off = 32; off > 0; off >>= 1) part += __shfl_xor(part, off, 64);
    if (lane == 0) out[wid] = part + b2[0];
}

// ===========================================================================
extern "C" void kernel_launch(void* const* d_in, const int* in_sizes, int n_in,
                              void* d_out, int out_size, void* d_ws, size_t ws_size,
                              hipStream_t stream) {
    const float* xd = (const float*)d_in[0];
    const int* A_ei = (const int*)d_in[1];
    const float* Aattr = (const float*)d_in[2];
    const int* E_ei = (const int*)d_in[3];
    const float* Eattr = (const float*)d_in[4];
    const float* AW = (const float*)d_in[6];
    const float* pe_g = (const float*)d_in[7];
    const float* pe_bt = (const float*)d_in[8];
    const float* pe_w = (const float*)d_in[9];
    const float* pe_b = (const float*)d_in[10];
    const float* gine_ew = (const float*)d_in[11];
    const float* gine_eb = (const float*)d_in[12];
    const float* gine_w1 = (const float*)d_in[13];
    const float* gine_b1 = (const float*)d_in[14];
    const float* gine_w2 = (const float*)d_in[15];
    const float* gine_b2 = (const float*)d_in[16];
    const float* wq = (const float*)d_in[17];
    const float* wk = (const float*)d_in[18];
    const float* wv = (const float*)d_in[19];
    const float* wo = (const float*)d_in[20];
    const float* bq = (const float*)d_in[21];
    const float* bk = (const float*)d_in[22];
    const float* bv = (const float*)d_in[23];
    const float* bo = (const float*)d_in[24];
    const float* n1g = (const float*)d_in[25];
    const float* n2g = (const float*)d_in[26];
    const float* n3g = (const float*)d_in[27];
    const float* n1b = (const float*)d_in[28];
    const float* n2b = (const float*)d_in[29];
    const float* n3b = (const float*)d_in[30];
    const float* mw1 = (const float*)d_in[31];
    const float* mb1 = (const float*)d_in[32];
    const float* mw2 = (const float*)d_in[33];
    const float* mb2 = (const float*)d_in[34];
    const float* ew1 = (const float*)d_in[35];
    const float* eb1 = (const float*)d_in[36];
    const float* ew2 = (const float*)d_in[37];
    const float* eb2 = (const float*)d_in[38];

    float* ws = (float*)d_ws;
    size_t off = 0;
    auto alloc = [&](size_t n) { float* p = ws + off; off += n; return p; };
    float* Aemb = alloc((size_t)EA * EEMB);
    float* Eemb = alloc((size_t)EE * EEMB);
    float* h = alloc((size_t)N_NODES * C);
    float* aggr = alloc((size_t)N_NODES * C);
    float* u = alloc((size_t)N_NODES * C);
    float* s1 = alloc((size_t)N_NODES * C);
    float* qb = alloc((size_t)N_NODES * C);
    float* kb = alloc((size_t)N_NODES * C);
    float* vb = alloc((size_t)N_NODES * C);
    float* ob = alloc((size_t)N_NODES * C);
    float* s2 = alloc((size_t)N_NODES * C);
    float* out3 = alloc((size_t)N_NODES * C);
    float* u2 = alloc((size_t)N_NODES * 176);
    float* stats = alloc(2048);
    float* st1 = stats;
    float* st2 = stats + 176;
    float* st3 = stats + 352;
    float* pe_mean = stats + 576;
    float* pe_rstd = stats + 608;

    const int NT = 256;
    const int nc_blocks = (N_NODES * C + NT - 1) / NT;
    const dim3 gA(512, 1, 1), gQKV(512, 1, 3), gU2(512, 2, 1);

    // --- prologue ---
    k_edge_emb3<<<1024, 256, 0, stream>>>(Aattr, Eattr, AW, Aemb, Eemb);
    k_colstats<<<PE_RAW, NT, 0, stream>>>(xd + XF, XD, N_NODES, pe_mean, pe_rstd);
    k_build_h<<<nc_blocks, NT, 0, stream>>>(xd, pe_mean, pe_rstd, pe_g, pe_bt, pe_w, pe_b, h);

    // --- layers ---
    for (int l = 0; l < NL; l++) {
        const float* ew = gine_ew + (size_t)l * EEMB * C;
        const float* eb = gine_eb + (size_t)l * C;
        const float* w1 = gine_w1 + (size_t)l * C * C;
        const float* b1 = gine_b1 + (size_t)l * C;
        const float* w2 = gine_w2 + (size_t)l * C * C;
        const float* b2 = gine_b2 + (size_t)l * C;
        const float* lwq = wq + (size_t)l * C * C;
        const float* lwk = wk + (size_t)l * C * C;
        const float* lwv = wv + (size_t)l * C * C;
        const float* lwo = wo + (size_t)l * C * C;
        const float* lbq = bq + (size_t)l * C;
        const float* lbk = bk + (size_t)l * C;
        const float* lbv = bv + (size_t)l * C;
        const float* lbo = bo + (size_t)l * C;
        const float* l1g = n1g + (size_t)l * C;
        const float* l1b = n1b + (size_t)l * C;
        const float* l2g = n2g + (size_t)l * C;
        const float* l2b = n2b + (size_t)l * C;
        const float* l3g = n3g + (size_t)l * C;
        const float* l3b = n3b + (size_t)l * C;
        const float* lmw1 = mw1 + (size_t)l * C * 176;
        const float* lmb1 = mb1 + (size_t)l * 176;
        const float* lmw2 = mw2 + (size_t)l * 176 * C;
        const float* lmb2 = mb2 + (size_t)l * C;

        hipMemsetAsync(aggr, 0, (size_t)N_NODES * C * sizeof(float), stream);
        hipMemsetAsync(stats, 0, 528 * sizeof(float), stream);
        k_gine_edge2<<<(EA * 22) / 256, 256, 0, stream>>>(Aemb, A_ei, h, ew, eb, aggr);
        // u = relu((h+aggr)@w1 + b1)
        k_gemm3<<<gA, 192, 0, stream>>>(h, aggr, C, w1, w1, w1, b1, b1, b1,
                                        u, u, u, C, C, 1, nullptr);
        // s1 = u@w2 + b2 + h  (+stats1)
        k_gemm3r<<<gA, 192, 0, stream>>>(u, C, w2, b2, h, s1, C, C, st1);
        // q,k,v fused via z
        k_gemm3<<<gQKV, 192, 0, stream>>>(h, nullptr, C, lwq, lwk, lwv, lbq, lbk, lbv,
                                          qb, kb, vb, C, C, 0, nullptr);
        k_attn<<<N_GRAPHS * NH * 4, 128, 0, stream>>>(qb, kb, vb, ob);
        // s2 = o@wo + bo + h  (+stats2)
        k_gemm3r<<<gA, 192, 0, stream>>>(ob, C, lwo, lbo, h, s2, C, C, st2);
        k_out3<<<nc_blocks, NT, 0, stream>>>(s1, s2, st1, st2, l1g, l1b, l2g, l2b, out3);
        // u2 = relu(out3@mw1 + mb1)   (176 cols -> y=2)
        k_gemm3<<<gU2, 192, 0, stream>>>(out3, nullptr, C, lmw1, lmw1, lmw1,
                                         lmb1, lmb1, lmb1, u2, u2, u2, 176, 176, 1, nullptr);
        // s3 = u2@mw2 + mb2 + out3  (+stats3)
        k_gemm3r<<<gA, 192, 0, stream>>>(u2, 176, lmw2, lmb2, out3, s1, C, C, st3);
        k_bn_apply<<<nc_blocks, NT, 0, stream>>>(s1, st3, l3g, l3b, h);
    }

    // --- epilogue: factored edge MLP ---
    k_gemm3r<<<gA, 192, 0, stream>>>(h, C, ew1, eb1, nullptr, qb, C, C, nullptr);                 // P
    k_gemm3r<<<gA, 192, 0, stream>>>(h, C, ew1 + (size_t)C * C, nullptr, nullptr, kb, C, C, nullptr); // Q
    k_final2<<<(EE * 64 + NT - 1) / NT, NT, 0, stream>>>(qb, kb, E_ei, Eemb,
                                                         ew1 + (size_t)2 * C * C, ew2, eb2,
                                                         (float*)d_out);
}